// Round 3
// baseline (374.125 us; speedup 1.0000x reference)
//
#include <hip/hip_runtime.h>
#include <hip/hip_cooperative_groups.h>
#include <math.h>

namespace cg = cooperative_groups;

#define TOKDIM   256
#define DD       768
#define HDIM     512
#define LOCALDIM 16384
#define FEATDIM  16640            // 16384 + 256
#define BB       64
#define THRESH   0.7f
#define GRID     512              // 64 batches x 8 unit-chunks

// workspace layout (float offsets)
#define WS_PG   0                           // [8][64][256] partial g (by unit-chunk)
#define WS_INV  (8*BB*TOKDIM)               // [64]
#define WS_GNT  (WS_INV + BB)               // [256][64] gn transposed
#define WS_SIM  (WS_GNT + TOKDIM*BB)        // [64][64]

// The NetVLAD local branch is identically 1.0 everywhere:
// softmax(axis=1).sum(axis=1) == 1 for any input. Only the global MLP,
// the norm, and the covisibility mask require computation.
__global__ __launch_bounds__(256) void mega_kernel(
    const float* __restrict__ gtok, const float* __restrict__ b1,
    const float* __restrict__ W1,   const float* __restrict__ W2,
    const float* __restrict__ b2,   const int* __restrict__ kptr,
    float* __restrict__ feats, float* __restrict__ mask,
    float* __restrict__ ws)
{
    cg::grid_group grid = cg::this_grid();
    const int blk = blockIdx.x, t = threadIdx.x;
    const int b = blk >> 3, uc = blk & 7;   // batch, 64-unit chunk

    __shared__ float xs[DD];                // batch token (reused as gi in phase C)
    __shared__ float hpart[4][BB];          // partial h (reused as sim partials)
    __shared__ float hs[BB];
    __shared__ float red[4];
    __shared__ float sm[BB][BB + 1];        // phase D only
    __shared__ unsigned long long forced[BB];

    // ---- Phase A: layer1 (this block's 64 units) + layer2 partial ----
    for (int i = t; i < DD; i += 256) xs[i] = gtok[b * DD + i];
    __syncthreads();
    {
        const int u = t & 63, q = t >> 6;   // 4 threads per unit, 192-d slices
        float h = 0.f;
        const float* w = W1 + (size_t)(q * 192) * HDIM + uc * 64 + u;
        #pragma unroll 8
        for (int d = 0; d < 192; ++d) { h = fmaf(xs[q * 192 + d], *w, h); w += HDIM; }
        hpart[q][u] = h;
    }
    __syncthreads();
    if (t < BB) {
        const float h = b1[uc * 64 + t] + hpart[0][t] + hpart[1][t] + hpart[2][t] + hpart[3][t];
        hs[t] = fmaxf(h, 0.f);
    }
    __syncthreads();
    {
        float s = 0.f;
        const float* w = W2 + (size_t)(uc * 64) * TOKDIM + t;
        #pragma unroll 8
        for (int j = 0; j < BB; ++j) { s = fmaf(hs[j], *w, s); w += TOKDIM; }
        ws[WS_PG + ((size_t)uc * BB + b) * TOKDIM + t] = s;
    }
    __threadfence();
    grid.sync();

    // ---- Phase B: full g (redundant x8 per batch), inv, fill, gn ----
    {
        float g = b2[t];
        #pragma unroll
        for (int c = 0; c < 8; ++c) g += ws[WS_PG + ((size_t)c * BB + b) * TOKDIM + t];
        float s2 = g * g;
        #pragma unroll
        for (int off = 32; off > 0; off >>= 1) s2 += __shfl_down(s2, off);
        if ((t & 63) == 0) red[t >> 6] = s2;
        __syncthreads();
        const float ssq = red[0] + red[1] + red[2] + red[3];
        const float inv = 1.f / fmaxf(sqrtf((float)LOCALDIM + ssq), 1e-12f);
        // fill this block's 1/8 of the local part (512 float4)
        float4* f4 = (float4*)(feats + (size_t)b * FEATDIM) + uc * 512;
        const float4 v = make_float4(inv, inv, inv, inv);
        f4[t] = v; f4[t + 256] = v;
        if (uc == 0) {
            const float gn = g * inv;
            feats[(size_t)b * FEATDIM + LOCALDIM + t] = gn;
            ws[WS_GNT + (size_t)t * BB + b] = gn;
            if (t == 0) ws[WS_INV + b] = inv;
        }
    }
    __threadfence();
    grid.sync();

    // ---- Phase C: blocks 0..63 compute one sim row each ----
    if (blk < BB) {
        xs[t] = feats[(size_t)blk * FEATDIM + LOCALDIM + t];   // gi
        __syncthreads();
        const int q = t >> 6, j = t & 63;
        float s = 0.f;
        const float* gT = ws + WS_GNT + (size_t)(q * 64) * BB + j;
        #pragma unroll 8
        for (int d = 0; d < 64; ++d) { s = fmaf(xs[q * 64 + d], gT[0], s); gT += BB; }
        hpart[q][j] = s;
        __syncthreads();
        if (t < BB) {
            const float invi = ws[WS_INV + blk], invj = ws[WS_INV + t];
            ws[WS_SIM + blk * BB + t] = (float)LOCALDIM * invi * invj
                + hpart[0][t] + hpart[1][t] + hpart[2][t] + hpart[3][t];
        }
    }
    __threadfence();
    grid.sync();

    // ---- Phase D: block 0: wave-parallel top-k + mask ----
    if (blk != 0) return;
    for (int e = t; e < BB * BB; e += 256) sm[e >> 6][e & 63] = ws[WS_SIM + e];
    if (t < BB) forced[t] = 1ull << t;      // diagonal
    __syncthreads();
    int k = *kptr; if (k > BB) k = BB;
    const int wid = t >> 6, lane = t & 63;
    for (int r = wid; r < BB; r += 4) {     // 4 waves x 16 rows
        float v = sm[r][lane];
        unsigned long long rowbits = 0;
        for (int p = 0; p < k; ++p) {
            float m = v;
            #pragma unroll
            for (int off = 32; off > 0; off >>= 1) m = fmaxf(m, __shfl_xor(m, off));
            const unsigned long long ball = __ballot(v == m);
            const int bi = __ffsll(ball) - 1;           // ties -> lowest index
            rowbits |= 1ull << bi;
            if (lane == bi) v = -INFINITY;
            if (lane == 0) atomicOr(&forced[bi], 1ull << r);   // mask[idx, row] = 1
        }
        if (lane == 0) atomicOr(&forced[r], rowbits);          // mask[row, idx] = 1
    }
    __syncthreads();
    for (int e = t; e < BB * BB; e += 256) {
        const int i = e >> 6, j = e & 63;
        mask[e] = ((sm[i][j] > THRESH) || ((forced[i] >> j) & 1ull)) ? 1.f : 0.f;
    }
}

extern "C" void kernel_launch(void* const* d_in, const int* in_sizes, int n_in,
                              void* d_out, int out_size, void* d_ws, size_t ws_size,
                              hipStream_t stream) {
    const float* gtok = (const float*)d_in[1];
    const float* W1g  = (const float*)d_in[6];
    const float* b1g  = (const float*)d_in[7];
    const float* W2g  = (const float*)d_in[8];
    const float* b2g  = (const float*)d_in[9];
    const int*   kp   = (const int*)d_in[10];

    float* feats = (float*)d_out;                     // [64, 16640]
    float* mask  = feats + (size_t)BB * FEATDIM;      // [64, 64]
    float* ws    = (float*)d_ws;

    void* args[] = { (void*)&gtok, (void*)&b1g, (void*)&W1g, (void*)&W2g,
                     (void*)&b2g, (void*)&kp, (void*)&feats, (void*)&mask,
                     (void*)&ws };
    hipLaunchCooperativeKernel((const void*)mega_kernel, dim3(GRID), dim3(256),
                               args, 0, stream);
}

// Round 4
// 91.558 us; speedup vs baseline: 4.0862x; 4.0862x over previous
//
#include <hip/hip_runtime.h>
#include <math.h>

#define TOKDIM   256
#define DD       768
#define HDIM     512
#define LOCALDIM 16384
#define FEATDIM  16640            // 16384 + 256
#define BB       64
#define THRESH   0.7f
#define GRID     512              // 64 batches x 8 unit-chunks; 2 blocks/CU -> co-resident
#define ONEF     0x3f800000u      // bit pattern of 1.0f

// workspace layout (float offsets)
#define WS_PG    0                            // [8][64][256] partial g (by unit-chunk)
#define WS_INV   (8*BB*TOKDIM)                // [64] 1/norm
#define WS_GNT   (WS_INV + BB)                // [256][64] gn transposed
#define WS_BAR   (WS_GNT + TOKDIM*BB)         // uint cells: [0..63] per-batch, [64] global
#define WS_BAR_BYTES (WS_BAR * 4)             // = 590080
#define BAR_LEN  (65 * 4)

// Device-scope counting barrier. Cells zeroed by hipMemsetAsync each launch.
// Release on arrive (flushes this block's prior plain stores to the coherent
// point), acquire after spin (invalidates stale L1/L2 before reads).
__device__ __forceinline__ void bar_wait(unsigned* cell, unsigned target, int t) {
    __syncthreads();
    if (t == 0) {
        __hip_atomic_fetch_add(cell, 1u, __ATOMIC_ACQ_REL, __HIP_MEMORY_SCOPE_AGENT);
        while (__hip_atomic_load(cell, __ATOMIC_RELAXED, __HIP_MEMORY_SCOPE_AGENT) < target)
            __builtin_amdgcn_s_sleep(1);
        (void)__hip_atomic_load(cell, __ATOMIC_ACQUIRE, __HIP_MEMORY_SCOPE_AGENT);
    }
    __syncthreads();
}

// NetVLAD local branch is identically 1.0 (softmax(axis=1).sum(axis=1) == 1),
// so feats = [inv * ones(16384), g/norm], norm = sqrt(16384 + ||g||^2).
__global__ __launch_bounds__(256) void mega_kernel(
    const float* __restrict__ gtok, const float* __restrict__ b1,
    const float* __restrict__ W1,   const float* __restrict__ W2,
    const float* __restrict__ b2,   const int* __restrict__ kptr,
    float* __restrict__ feats, unsigned* __restrict__ maskU,
    float* __restrict__ ws,    unsigned* __restrict__ bar)
{
    const int blk = blockIdx.x, t = threadIdx.x;
    const int b = blk >> 3, uc = blk & 7;     // batch, 64-unit chunk

    __shared__ float xs[DD];                  // token (reused as gi in phase C)
    __shared__ float hpart[4][BB];            // h partials (reused as sim partials)
    __shared__ float hs[BB];
    __shared__ float red[4];

    // block 0: zero the mask (plain stores; flushed by its barrier-1 release,
    // long before any phase-C atomicOr can touch it)
    if (blk == 0) {
        uint4 z = make_uint4(0u, 0u, 0u, 0u);
        uint4* m4 = (uint4*)maskU;            // 4096 words = 1024 uint4
        m4[t] = z; m4[t + 256] = z; m4[t + 512] = z; m4[t + 768] = z;
    }

    // ---- Phase A: layer1 for this block's 64 units + layer2 partial ----
    for (int i = t; i < DD; i += 256) xs[i] = gtok[b * DD + i];
    __syncthreads();
    {
        const int u = t & 63, q = t >> 6;     // 4 threads per unit, 192-d slices
        float h = 0.f;
        const float* w = W1 + (size_t)(q * 192) * HDIM + uc * 64 + u;
        #pragma unroll 8
        for (int d = 0; d < 192; ++d) { h = fmaf(xs[q * 192 + d], *w, h); w += HDIM; }
        hpart[q][u] = h;
    }
    __syncthreads();
    if (t < BB) {
        const float h = b1[uc * 64 + t] + hpart[0][t] + hpart[1][t] + hpart[2][t] + hpart[3][t];
        hs[t] = fmaxf(h, 0.f);
    }
    __syncthreads();
    {
        float s = 0.f;
        const float* w = W2 + (size_t)(uc * 64) * TOKDIM + t;
        #pragma unroll 8
        for (int j = 0; j < BB; ++j) { s = fmaf(hs[j], *w, s); w += TOKDIM; }
        ws[WS_PG + ((size_t)uc * BB + b) * TOKDIM + t] = s;
    }

    // ---- per-batch barrier (8 arrivals): batch b proceeds independently ----
    bar_wait(bar + b, 8u, t);

    // ---- Phase B: full g (redundant x8), inv, feats fill, gn/gnT ----
    {
        float g = b2[t];
        #pragma unroll
        for (int c = 0; c < 8; ++c) g += ws[WS_PG + ((size_t)c * BB + b) * TOKDIM + t];
        float s2 = g * g;
        #pragma unroll
        for (int off = 32; off > 0; off >>= 1) s2 += __shfl_down(s2, off);
        if ((t & 63) == 0) red[t >> 6] = s2;
        __syncthreads();
        const float ssq = red[0] + red[1] + red[2] + red[3];
        const float inv = 1.f / fmaxf(sqrtf((float)LOCALDIM + ssq), 1e-12f);
        float4* f4 = (float4*)(feats + (size_t)b * FEATDIM) + uc * 512;
        const float4 v = make_float4(inv, inv, inv, inv);
        f4[t] = v; f4[t + 256] = v;           // this block's 1/8 of the local fill
        if (uc == 0) {
            const float gn = g * inv;
            feats[(size_t)b * FEATDIM + LOCALDIM + t] = gn;
            ws[WS_GNT + (size_t)t * BB + b] = gn;
            if (t == 0) ws[WS_INV + b] = inv;
        }
    }

    // ---- global barrier (512 arrivals) ----
    bar_wait(bar + BB, (unsigned)GRID, t);

    if (blk >= BB) return;

    // ---- Phase C: block i = sim row i + top-k + atomicOr mask writes ----
    const int i = blk;
    xs[t] = feats[(size_t)i * FEATDIM + LOCALDIM + t];   // gi
    __syncthreads();
    {
        const int q = t >> 6, j = t & 63;
        float s = 0.f;
        const float* gT = ws + WS_GNT + (size_t)(q * 64) * BB + j;
        #pragma unroll 8
        for (int d = 0; d < 64; ++d) { s = fmaf(xs[q * 64 + d], gT[0], s); gT += BB; }
        hpart[q][j] = s;
    }
    __syncthreads();
    if (t < BB) {                            // exactly wave 0: full 64-lane wave
        const float invi = ws[WS_INV + i], invj = ws[WS_INV + t];
        const float sv = (float)LOCALDIM * invi * invj
                       + hpart[0][t] + hpart[1][t] + hpart[2][t] + hpart[3][t];
        int k = *kptr; if (k > BB) k = BB;
        float v = sv;
        unsigned long long rowbits = 0;
        for (int p = 0; p < k; ++p) {        // ties -> lowest index (jax top_k)
            float m = v;
            #pragma unroll
            for (int off = 32; off > 0; off >>= 1) m = fmaxf(m, __shfl_xor(m, off));
            const unsigned long long ball = __ballot(v == m);
            const int bi = __ffsll(ball) - 1;
            rowbits |= 1ull << bi;
            if (t == bi) v = -INFINITY;
            if (t == 0) atomicOr(&maskU[bi * BB + i], ONEF);   // mask[idx, row] = 1
        }
        const unsigned base =
            ((sv > THRESH) || (t == i) || ((rowbits >> t) & 1ull)) ? ONEF : 0u;
        if (base) atomicOr(&maskU[i * BB + t], base);          // row i (incl. diag/topk)
    }
}

extern "C" void kernel_launch(void* const* d_in, const int* in_sizes, int n_in,
                              void* d_out, int out_size, void* d_ws, size_t ws_size,
                              hipStream_t stream) {
    const float* gtok = (const float*)d_in[1];
    const float* W1g  = (const float*)d_in[6];
    const float* b1g  = (const float*)d_in[7];
    const float* W2g  = (const float*)d_in[8];
    const float* b2g  = (const float*)d_in[9];
    const int*   kp   = (const int*)d_in[10];

    float*    feats = (float*)d_out;                       // [64, 16640]
    unsigned* maskU = (unsigned*)(feats + (size_t)BB * FEATDIM);  // [64,64] as bits
    float*    ws    = (float*)d_ws;
    unsigned* bar   = (unsigned*)((char*)d_ws + WS_BAR_BYTES);

    // zero barrier cells (graph-legal memset node), then the single kernel
    hipMemsetAsync((void*)bar, 0, BAR_LEN, stream);
    hipLaunchKernelGGL(mega_kernel, dim3(GRID), dim3(256), 0, stream,
                       gtok, b1g, W1g, W2g, b2g, kp, feats, maskU, ws, bar);
}

// Round 5
// 39.996 us; speedup vs baseline: 9.3541x; 2.2892x over previous
//
#include <hip/hip_runtime.h>
#include <math.h>

#define TOKDIM   256
#define DD       768
#define HDIM     512
#define LOCALDIM 16384
#define FEATDIM  16640            // 16384 + 256
#define BB       64
#define THRESH   0.7f
#define GRID     512              // 64 batches x 8 unit-chunks; small LDS/VGPR -> co-resident
#define ONEF     0x3f800000u      // bit pattern of 1.0f

// workspace float offsets
#define WS_PG    0                            // [8][64][256] partial g (by unit-chunk)
#define WS_INV   (8*BB*TOKDIM)                // [64] 1/norm
#define WS_GN    (WS_INV + BB)                // [64][256] gn row-major
#define WS_GNT   (WS_GN + BB*TOKDIM)          // [256][64] gn transposed
#define WS_CELL  (WS_GNT + TOKDIM*BB)         // uint cells: cell1[64], cell2[64], cell3[1]
#define WS_CELL_BYTES (WS_CELL * 4)
#define CELL_LEN (129 * 4)

// All cross-block data uses RELAXED/AGENT atomics (per-access coherent at the
// device coherence point) -> barriers need NO cache-wide flush/invalidate.
__device__ __forceinline__ void st_agent(float* p, float v) {
    __hip_atomic_store(p, v, __ATOMIC_RELAXED, __HIP_MEMORY_SCOPE_AGENT);
}
__device__ __forceinline__ float ld_agent(float* p) {
    return __hip_atomic_load(p, __ATOMIC_RELAXED, __HIP_MEMORY_SCOPE_AGENT);
}

// arrive: drain this wave's write-through stores, block-barrier, t0 bumps cell.
__device__ __forceinline__ void bar_arrive(unsigned* cell, int t) {
    asm volatile("s_waitcnt vmcnt(0)" ::: "memory");
    __syncthreads();   // compiler also drains all waves' vmcnt before s_barrier
    if (t == 0)
        __hip_atomic_fetch_add(cell, 1u, __ATOMIC_RELAXED, __HIP_MEMORY_SCOPE_AGENT);
}
__device__ __forceinline__ void bar_spin(unsigned* cell, unsigned target, int t) {
    if (t == 0) {
        while (__hip_atomic_load(cell, __ATOMIC_RELAXED, __HIP_MEMORY_SCOPE_AGENT) < target)
            __builtin_amdgcn_s_sleep(2);
        asm volatile("" ::: "memory");   // no hoisting of later loads above the spin
    }
    __syncthreads();
}

// NetVLAD local branch is identically 1.0 (softmax(axis=1).sum(axis=1) == 1),
// so feats = [inv * ones(16384), g/norm], norm = sqrt(16384 + ||g||^2).
__global__ __launch_bounds__(256) void mega_kernel(
    const float* __restrict__ gtok, const float* __restrict__ b1,
    const float* __restrict__ W1,   const float* __restrict__ W2,
    const float* __restrict__ b2,   const int* __restrict__ kptr,
    float* __restrict__ feats, unsigned* __restrict__ maskU,
    float* __restrict__ ws,    unsigned* __restrict__ bar)
{
    const int blk = blockIdx.x, t = threadIdx.x;
    const int b = blk >> 3, uc = blk & 7;     // batch, 64-unit chunk
    unsigned* cell1 = bar;                    // [64] per-batch, phase A done
    unsigned* cell2 = bar + 64;               // [64] per-batch, phase B done
    unsigned* cell3 = bar + 128;              // [1]  all batches done

    __shared__ float xs[DD];                  // token (reused as gi in phase C)
    __shared__ float hpart[4][BB];            // h partials (reused as sim partials)
    __shared__ float hs[BB];
    __shared__ float red[4];

    // block 0 zeroes the mask at the coherence point (ordered before any
    // phase-C atomicOr via cell1[0] -> cell2[0] -> cell3 transitivity)
    if (blk == 0)
        for (int i = t; i < BB * BB; i += 256)
            __hip_atomic_store(maskU + i, 0u, __ATOMIC_RELAXED, __HIP_MEMORY_SCOPE_AGENT);

    // ---- Phase A: layer1 for this block's 64 units + layer2 partial ----
    for (int i = t; i < DD; i += 256) xs[i] = gtok[b * DD + i];
    __syncthreads();
    {
        const int u = t & 63, q = t >> 6;     // 4 threads per unit, 192-d slices
        float h = 0.f;
        const float* w = W1 + (size_t)(q * 192) * HDIM + uc * 64 + u;
        #pragma unroll 8
        for (int d = 0; d < 192; ++d) { h = fmaf(xs[q * 192 + d], *w, h); w += HDIM; }
        hpart[q][u] = h;
    }
    __syncthreads();
    if (t < BB) {
        const float h = b1[uc * 64 + t] + hpart[0][t] + hpart[1][t] + hpart[2][t] + hpart[3][t];
        hs[t] = fmaxf(h, 0.f);
    }
    __syncthreads();
    {
        float s = 0.f;
        const float* w = W2 + (size_t)(uc * 64) * TOKDIM + t;
        #pragma unroll 8
        for (int j = 0; j < BB; ++j) { s = fmaf(hs[j], *w, s); w += TOKDIM; }
        st_agent(ws + WS_PG + ((size_t)uc * BB + b) * TOKDIM + t, s);
    }
    bar_arrive(cell1 + b, t);

    // ---- per-batch wait: batch b proceeds as soon as its 8 blocks finish ----
    bar_spin(cell1 + b, 8u, t);

    // ---- Phase B: full g (redundant x8), inv, feats fill, gn/gnT ----
    {
        float g = b2[t];
        #pragma unroll
        for (int c = 0; c < 8; ++c)
            g += ld_agent(ws + WS_PG + ((size_t)c * BB + b) * TOKDIM + t);
        float s2 = g * g;
        #pragma unroll
        for (int off = 32; off > 0; off >>= 1) s2 += __shfl_down(s2, off);
        if ((t & 63) == 0) red[t >> 6] = s2;
        __syncthreads();
        const float ssq = red[0] + red[1] + red[2] + red[3];
        const float inv = 1.f / fmaxf(sqrtf((float)LOCALDIM + ssq), 1e-12f);
        float4* f4 = (float4*)(feats + (size_t)b * FEATDIM) + uc * 512;
        const float4 v = make_float4(inv, inv, inv, inv);
        f4[t] = v; f4[t + 256] = v;           // this block's 1/8 of the local fill
        if (uc == 0) {
            const float gn = g * inv;
            feats[(size_t)b * FEATDIM + LOCALDIM + t] = gn;
            st_agent(ws + WS_GN  + (size_t)b * TOKDIM + t, gn);
            st_agent(ws + WS_GNT + (size_t)t * BB + b, gn);
            if (t == 0) st_agent(ws + WS_INV + b, inv);
        }
    }
    // hierarchical arrival: 8 per batch cell; 8th arriver promotes to cell3
    asm volatile("s_waitcnt vmcnt(0)" ::: "memory");
    __syncthreads();
    if (t == 0) {
        const unsigned old =
            __hip_atomic_fetch_add(cell2 + b, 1u, __ATOMIC_RELAXED, __HIP_MEMORY_SCOPE_AGENT);
        if (old == 7u)
            __hip_atomic_fetch_add(cell3, 1u, __ATOMIC_RELAXED, __HIP_MEMORY_SCOPE_AGENT);
    }
    if (blk >= BB) return;                    // only blocks 0..63 run phase C

    bar_spin(cell3, (unsigned)BB, t);

    // ---- Phase C: block i = sim row i + top-k + atomicOr mask writes ----
    const int i = blk;
    xs[t] = ld_agent(ws + WS_GN + (size_t)i * TOKDIM + t);   // gi
    __syncthreads();
    {
        const int q = t >> 6, j = t & 63;
        float s = 0.f;
        float* gT = ws + WS_GNT + (size_t)(q * 64) * BB + j;
        #pragma unroll 8
        for (int d = 0; d < 64; ++d) { s = fmaf(xs[q * 64 + d], ld_agent(gT), s); gT += BB; }
        hpart[q][j] = s;
    }
    __syncthreads();
    if (t < BB) {                             // exactly wave 0: full 64-lane wave
        const float invi = ld_agent(ws + WS_INV + i);
        const float invj = ld_agent(ws + WS_INV + t);
        const float sv = (float)LOCALDIM * invi * invj
                       + hpart[0][t] + hpart[1][t] + hpart[2][t] + hpart[3][t];
        int k = *kptr; if (k > BB) k = BB;
        float v = sv;
        unsigned long long rowbits = 0;
        for (int p = 0; p < k; ++p) {         // ties -> lowest index (jax top_k)
            float m = v;
            #pragma unroll
            for (int off = 32; off > 0; off >>= 1) m = fmaxf(m, __shfl_xor(m, off));
            const unsigned long long ball = __ballot(v == m);
            const int bi = __ffsll(ball) - 1;
            rowbits |= 1ull << bi;
            if (t == bi) v = -INFINITY;
            if (t == 0) atomicOr(&maskU[bi * BB + i], ONEF);   // mask[idx, row] = 1
        }
        const unsigned base =
            ((sv > THRESH) || (t == i) || ((rowbits >> t) & 1ull)) ? ONEF : 0u;
        if (base) atomicOr(&maskU[i * BB + t], base);          // row i (diag/topk/thresh)
    }
}

extern "C" void kernel_launch(void* const* d_in, const int* in_sizes, int n_in,
                              void* d_out, int out_size, void* d_ws, size_t ws_size,
                              hipStream_t stream) {
    const float* gtok = (const float*)d_in[1];
    const float* W1g  = (const float*)d_in[6];
    const float* b1g  = (const float*)d_in[7];
    const float* W2g  = (const float*)d_in[8];
    const float* b2g  = (const float*)d_in[9];
    const int*   kp   = (const int*)d_in[10];

    float*    feats = (float*)d_out;                              // [64, 16640]
    unsigned* maskU = (unsigned*)(feats + (size_t)BB * FEATDIM);  // [64,64] as bits
    float*    ws    = (float*)d_ws;
    unsigned* bar   = (unsigned*)((char*)d_ws + WS_CELL_BYTES);

    // zero the 129 barrier cells (graph-legal memset node), then the kernel
    hipMemsetAsync((void*)bar, 0, CELL_LEN, stream);
    hipLaunchKernelGGL(mega_kernel, dim3(GRID), dim3(256), 0, stream,
                       gtok, b1g, W1g, W2g, b2g, kp, feats, maskU, ws, bar);
}